// Round 1
// baseline (662.169 us; speedup 1.0000x reference)
//
#include <hip/hip_runtime.h>
#include <math.h>

// TemporalEncoder: out[t, b, d] = (t == floor(sigmoid(x[b,d]) * (T-1))) ? 1 : 0
// B=256, D=4096, T=100. Output 419 MB fp32 -> pure write-BW bound.
//
// Structure (two passes, d_ws holds spike times as uchar):
//   Pass 1: spike times -> d_ws (1 MB). Tiny.
//   Pass 2: output-major 2D grid, sequential write stream (fill-shaped).
//
// R2 change: pass 2 went from 1 uchar4 load : 1 f32x4 store per thread to
// 1 dwordx4 (uchar16) load : 4 f32x4 NONTEMPORAL stores per thread.
//  - 4x store ILP behind each dependent load (load latency no longer gates
//    store issue 1:1).
//  - nt stores keep the 419 MB write stream from evicting the 1 MB st table
//    out of L2 (it is re-read by all 100 t-planes -> ~100 MB of reads that
//    must stay L2-hit).

typedef __attribute__((ext_vector_type(4))) float f32x4;

__device__ __forceinline__ float sigmoidf_(float x) {
    return 1.0f / (1.0f + expf(-x));  // matches f32 expit to 0 ulp vs np ref (R1)
}

__global__ __launch_bounds__(256) void spike_time_kernel(
    const float* __restrict__ x, unsigned char* __restrict__ st,
    int n, float tm1) {
    const int e = (blockIdx.x * 256 + threadIdx.x) * 4;
    if (e + 3 < n) {
        f32x4 v = *reinterpret_cast<const f32x4*>(x + e);
        uchar4 s;
        s.x = (unsigned char)(int)(sigmoidf_(v.x) * tm1);
        s.y = (unsigned char)(int)(sigmoidf_(v.y) * tm1);
        s.z = (unsigned char)(int)(sigmoidf_(v.z) * tm1);
        s.w = (unsigned char)(int)(sigmoidf_(v.w) * tm1);
        *reinterpret_cast<uchar4*>(st + e) = s;
    } else {
        for (int i = e; i < n; ++i)
            st[i] = (unsigned char)(int)(sigmoidf_(x[i]) * tm1);
    }
}

// Pass 2: 16 elements per thread. One 16-B st load feeds four 16-B nt stores.
__global__ __launch_bounds__(256) void write_onehot16_kernel(
    const unsigned char* __restrict__ st, float* __restrict__ out, int n) {
    const int t = blockIdx.y;
    const unsigned int tu = (unsigned int)t;
    const int e = (blockIdx.x * 256 + threadIdx.x) * 16;
    float* op = out + (size_t)t * n + e;
    if (e + 15 < n) {
        const uint4 s = *reinterpret_cast<const uint4*>(st + e);
        const unsigned int words[4] = {s.x, s.y, s.z, s.w};
#pragma unroll
        for (int w = 0; w < 4; ++w) {
            const unsigned int sw = words[w];  // static index after unroll
            f32x4 o;
            o.x = (((sw      ) & 0xffu) == tu) ? 1.0f : 0.0f;
            o.y = (((sw >>  8) & 0xffu) == tu) ? 1.0f : 0.0f;
            o.z = (((sw >> 16) & 0xffu) == tu) ? 1.0f : 0.0f;
            o.w = (((sw >> 24)        ) == tu) ? 1.0f : 0.0f;
            __builtin_nontemporal_store(o, reinterpret_cast<f32x4*>(op) + w);
        }
    } else {
        for (int i = e; i < n; ++i)
            out[(size_t)t * n + i] = (st[i] == (unsigned char)t) ? 1.0f : 0.0f;
    }
}

// Fallback if d_ws is too small or T doesn't fit in a byte: fused recompute.
__global__ __launch_bounds__(256) void fused_onehot_kernel(
    const float* __restrict__ x, float* __restrict__ out, int n, float tm1) {
    const int t = blockIdx.y;
    const int e = (blockIdx.x * 256 + threadIdx.x) * 4;
    if (e + 3 < n) {
        f32x4 v = *reinterpret_cast<const f32x4*>(x + e);
        f32x4 o;
        o.x = ((int)(sigmoidf_(v.x) * tm1) == t) ? 1.0f : 0.0f;
        o.y = ((int)(sigmoidf_(v.y) * tm1) == t) ? 1.0f : 0.0f;
        o.z = ((int)(sigmoidf_(v.z) * tm1) == t) ? 1.0f : 0.0f;
        o.w = ((int)(sigmoidf_(v.w) * tm1) == t) ? 1.0f : 0.0f;
        __builtin_nontemporal_store(o, reinterpret_cast<f32x4*>(out + (size_t)t * n + e));
    } else {
        for (int i = e; i < n; ++i)
            out[(size_t)t * n + i] = ((int)(sigmoidf_(x[i]) * tm1) == t) ? 1.0f : 0.0f;
    }
}

extern "C" void kernel_launch(void* const* d_in, const int* in_sizes, int n_in,
                              void* d_out, int out_size, void* d_ws, size_t ws_size,
                              hipStream_t stream) {
    const float* x = (const float*)d_in[0];
    float* out = (float*)d_out;
    const int n = in_sizes[0];        // B*D = 1048576
    const int T = out_size / n;       // 100
    const float tm1 = (float)(T - 1);

    const int n4 = (n + 3) / 4;
    const int blocks4 = (n4 + 255) / 256;     // pass-1 / fused grid

    if (ws_size >= (size_t)n && T <= 256) {
        unsigned char* st = (unsigned char*)d_ws;
        spike_time_kernel<<<blocks4, 256, 0, stream>>>(x, st, n, tm1);
        const int blocks16 = (n + 4095) / 4096;   // 256 for n=1M
        dim3 grid(blocks16, T);
        write_onehot16_kernel<<<grid, 256, 0, stream>>>(st, out, n);
    } else {
        dim3 grid(blocks4, T);
        fused_onehot_kernel<<<grid, 256, 0, stream>>>(x, out, n, tm1);
    }
}

// Round 2
// 452.691 us; speedup vs baseline: 1.4627x; 1.4627x over previous
//
#include <hip/hip_runtime.h>
#include <math.h>

// TemporalEncoder: out[t, b, d] = (t == floor(sigmoid(x[b,d]) * (T-1))) ? 1 : 0
// B=256, D=4096, T=100. Output 419 MB fp32 -> pure write-BW bound.
//
// Structure (two passes, d_ws holds spike times as uchar):
//   Pass 1: spike times -> d_ws (1 MB). Tiny.
//   Pass 2: output-major 2D grid, sequential write stream (fill-shaped).
//           16 elems/thread: one dwordx4 st load -> four f32x4 stores.
//
// R2 lesson (counters): NONTEMPORAL stores caused 2.2x WRITE_SIZE
// amplification (928 MB for a 419 MB output) -- nt bypasses L2 write-back
// merging so each 16 B store became its own partial-line HBM transaction.
// BW collapsed to 2.7 TB/s. Regular stores let L2 merge into full 64 B
// line writebacks (fill kernel path, 6.25 TB/s). FETCH_SIZE=527 KB in R2
// proved the st-table reads are cache-resident and were never the issue.

typedef __attribute__((ext_vector_type(4))) float f32x4;

__device__ __forceinline__ float sigmoidf_(float x) {
    return 1.0f / (1.0f + expf(-x));  // matches f32 expit to 0 ulp vs np ref (R1)
}

__global__ __launch_bounds__(256) void spike_time_kernel(
    const float* __restrict__ x, unsigned char* __restrict__ st,
    int n, float tm1) {
    const int e = (blockIdx.x * 256 + threadIdx.x) * 4;
    if (e + 3 < n) {
        f32x4 v = *reinterpret_cast<const f32x4*>(x + e);
        uchar4 s;
        s.x = (unsigned char)(int)(sigmoidf_(v.x) * tm1);
        s.y = (unsigned char)(int)(sigmoidf_(v.y) * tm1);
        s.z = (unsigned char)(int)(sigmoidf_(v.z) * tm1);
        s.w = (unsigned char)(int)(sigmoidf_(v.w) * tm1);
        *reinterpret_cast<uchar4*>(st + e) = s;
    } else {
        for (int i = e; i < n; ++i)
            st[i] = (unsigned char)(int)(sigmoidf_(x[i]) * tm1);
    }
}

// Pass 2: 16 elements per thread. One 16-B st load feeds four 16-B stores
// (regular write-back stores; L2 merges them into 64-B line writebacks).
__global__ __launch_bounds__(256) void write_onehot16_kernel(
    const unsigned char* __restrict__ st, float* __restrict__ out, int n) {
    const int t = blockIdx.y;
    const unsigned int tu = (unsigned int)t;
    const int e = (blockIdx.x * 256 + threadIdx.x) * 16;
    float* op = out + (size_t)t * n + e;
    if (e + 15 < n) {
        const uint4 s = *reinterpret_cast<const uint4*>(st + e);
        const unsigned int words[4] = {s.x, s.y, s.z, s.w};
#pragma unroll
        for (int w = 0; w < 4; ++w) {
            const unsigned int sw = words[w];  // static index after unroll
            f32x4 o;
            o.x = (((sw      ) & 0xffu) == tu) ? 1.0f : 0.0f;
            o.y = (((sw >>  8) & 0xffu) == tu) ? 1.0f : 0.0f;
            o.z = (((sw >> 16) & 0xffu) == tu) ? 1.0f : 0.0f;
            o.w = (((sw >> 24)        ) == tu) ? 1.0f : 0.0f;
            *(reinterpret_cast<f32x4*>(op) + w) = o;
        }
    } else {
        for (int i = e; i < n; ++i)
            out[(size_t)t * n + i] = (st[i] == (unsigned char)t) ? 1.0f : 0.0f;
    }
}

// Fallback if d_ws is too small or T doesn't fit in a byte: fused recompute.
__global__ __launch_bounds__(256) void fused_onehot_kernel(
    const float* __restrict__ x, float* __restrict__ out, int n, float tm1) {
    const int t = blockIdx.y;
    const int e = (blockIdx.x * 256 + threadIdx.x) * 4;
    if (e + 3 < n) {
        f32x4 v = *reinterpret_cast<const f32x4*>(x + e);
        f32x4 o;
        o.x = ((int)(sigmoidf_(v.x) * tm1) == t) ? 1.0f : 0.0f;
        o.y = ((int)(sigmoidf_(v.y) * tm1) == t) ? 1.0f : 0.0f;
        o.z = ((int)(sigmoidf_(v.z) * tm1) == t) ? 1.0f : 0.0f;
        o.w = ((int)(sigmoidf_(v.w) * tm1) == t) ? 1.0f : 0.0f;
        *reinterpret_cast<f32x4*>(out + (size_t)t * n + e) = o;
    } else {
        for (int i = e; i < n; ++i)
            out[(size_t)t * n + i] = ((int)(sigmoidf_(x[i]) * tm1) == t) ? 1.0f : 0.0f;
    }
}

extern "C" void kernel_launch(void* const* d_in, const int* in_sizes, int n_in,
                              void* d_out, int out_size, void* d_ws, size_t ws_size,
                              hipStream_t stream) {
    const float* x = (const float*)d_in[0];
    float* out = (float*)d_out;
    const int n = in_sizes[0];        // B*D = 1048576
    const int T = out_size / n;       // 100
    const float tm1 = (float)(T - 1);

    const int n4 = (n + 3) / 4;
    const int blocks4 = (n4 + 255) / 256;     // pass-1 / fused grid

    if (ws_size >= (size_t)n && T <= 256) {
        unsigned char* st = (unsigned char*)d_ws;
        spike_time_kernel<<<blocks4, 256, 0, stream>>>(x, st, n, tm1);
        const int blocks16 = (n + 4095) / 4096;   // 256 for n=1M
        dim3 grid(blocks16, T);
        write_onehot16_kernel<<<grid, 256, 0, stream>>>(st, out, n);
    } else {
        dim3 grid(blocks4, T);
        fused_onehot_kernel<<<grid, 256, 0, stream>>>(x, out, n, tm1);
    }
}

// Round 3
// 417.058 us; speedup vs baseline: 1.5877x; 1.0854x over previous
//
#include <hip/hip_runtime.h>
#include <math.h>

// TemporalEncoder: out[t, b, d] = (t == floor(sigmoid(x[b,d]) * (T-1))) ? 1 : 0
// B=256, D=4096, T=100. Output 419 MB fp32 -> pure write-BW bound.
//
// Structure (two passes, d_ws holds spike times as uchar):
//   Pass 1: spike times -> d_ws (1 MB, L2-resident afterwards; R2 counters
//           proved FETCH_SIZE ~0.5 MB across all 100 planes).
//   Pass 2: output-major 2D grid, sequential write stream (fill-shaped).
//
// Hard-won layout lessons (counter-verified):
//   R2: nontemporal stores -> 2.2x WRITE_SIZE amplification (nt bypasses L2
//       write-back merging; each 16 B store became its own partial-line HBM
//       transaction). Regular stores only.
//   R3: 16 CONSECUTIVE elems/thread -> within one wave store instruction,
//       lanes write 16 B chunks at 64 B stride (every lane a different,
//       quarter-covered 64 B sector) -> 4x store transactions/instr, +50 us.
//   R4: 16 elems/thread as 4 chunks strided by 1024 elems: every load/store
//       instruction is fully lane-coalesced (256 B loads, 1 KB stores), and
//       we keep 4 independent load->store chains per thread for ILP.

typedef __attribute__((ext_vector_type(4))) float f32x4;

__device__ __forceinline__ float sigmoidf_(float x) {
    return 1.0f / (1.0f + expf(-x));  // matches f32 expit to 0 ulp vs np ref (R1)
}

__device__ __forceinline__ f32x4 onehot4_(unsigned int sw, unsigned int tu) {
    f32x4 o;
    o.x = (((sw      ) & 0xffu) == tu) ? 1.0f : 0.0f;
    o.y = (((sw >>  8) & 0xffu) == tu) ? 1.0f : 0.0f;
    o.z = (((sw >> 16) & 0xffu) == tu) ? 1.0f : 0.0f;
    o.w = (((sw >> 24)        ) == tu) ? 1.0f : 0.0f;
    return o;
}

__global__ __launch_bounds__(256) void spike_time_kernel(
    const float* __restrict__ x, unsigned char* __restrict__ st,
    int n, float tm1) {
    const int e = (blockIdx.x * 256 + threadIdx.x) * 4;
    if (e + 3 < n) {
        f32x4 v = *reinterpret_cast<const f32x4*>(x + e);
        uchar4 s;
        s.x = (unsigned char)(int)(sigmoidf_(v.x) * tm1);
        s.y = (unsigned char)(int)(sigmoidf_(v.y) * tm1);
        s.z = (unsigned char)(int)(sigmoidf_(v.z) * tm1);
        s.w = (unsigned char)(int)(sigmoidf_(v.w) * tm1);
        *reinterpret_cast<uchar4*>(st + e) = s;
    } else {
        for (int i = e; i < n; ++i)
            st[i] = (unsigned char)(int)(sigmoidf_(x[i]) * tm1);
    }
}

// Pass 2: block owns 4096 consecutive elements of one t-plane.
// Thread handles 4 chunks of 4 elements at stride 1024 elems:
// all loads/stores lane-coalesced, 4 independent chains per thread.
__global__ __launch_bounds__(256) void write_onehot_c4_kernel(
    const unsigned char* __restrict__ st, float* __restrict__ out, int n) {
    const int t = blockIdx.y;
    const unsigned int tu = (unsigned int)t;
    const int blockBase = blockIdx.x * 4096;
    const int e = blockBase + threadIdx.x * 4;
    const unsigned char* sp = st + e;
    float* op = out + (size_t)t * n + e;
    if (blockBase + 4096 <= n) {
        // Issue all 4 independent loads up front; compiler pipelines them.
        const unsigned int s0 = *reinterpret_cast<const unsigned int*>(sp);
        const unsigned int s1 = *reinterpret_cast<const unsigned int*>(sp + 1024);
        const unsigned int s2 = *reinterpret_cast<const unsigned int*>(sp + 2048);
        const unsigned int s3 = *reinterpret_cast<const unsigned int*>(sp + 3072);
        *reinterpret_cast<f32x4*>(op       ) = onehot4_(s0, tu);
        *reinterpret_cast<f32x4*>(op + 1024) = onehot4_(s1, tu);
        *reinterpret_cast<f32x4*>(op + 2048) = onehot4_(s2, tu);
        *reinterpret_cast<f32x4*>(op + 3072) = onehot4_(s3, tu);
    } else {
        for (int w = 0; w < 4; ++w) {
            const int ee = e + w * 1024;
            for (int i = ee; i < ee + 4 && i < n; ++i)
                out[(size_t)t * n + i] = (st[i] == (unsigned char)t) ? 1.0f : 0.0f;
        }
    }
}

// Fallback if d_ws is too small or T doesn't fit in a byte: fused recompute.
__global__ __launch_bounds__(256) void fused_onehot_kernel(
    const float* __restrict__ x, float* __restrict__ out, int n, float tm1) {
    const int t = blockIdx.y;
    const int e = (blockIdx.x * 256 + threadIdx.x) * 4;
    if (e + 3 < n) {
        f32x4 v = *reinterpret_cast<const f32x4*>(x + e);
        f32x4 o;
        o.x = ((int)(sigmoidf_(v.x) * tm1) == t) ? 1.0f : 0.0f;
        o.y = ((int)(sigmoidf_(v.y) * tm1) == t) ? 1.0f : 0.0f;
        o.z = ((int)(sigmoidf_(v.z) * tm1) == t) ? 1.0f : 0.0f;
        o.w = ((int)(sigmoidf_(v.w) * tm1) == t) ? 1.0f : 0.0f;
        *reinterpret_cast<f32x4*>(out + (size_t)t * n + e) = o;
    } else {
        for (int i = e; i < n; ++i)
            out[(size_t)t * n + i] = ((int)(sigmoidf_(x[i]) * tm1) == t) ? 1.0f : 0.0f;
    }
}

extern "C" void kernel_launch(void* const* d_in, const int* in_sizes, int n_in,
                              void* d_out, int out_size, void* d_ws, size_t ws_size,
                              hipStream_t stream) {
    const float* x = (const float*)d_in[0];
    float* out = (float*)d_out;
    const int n = in_sizes[0];        // B*D = 1048576
    const int T = out_size / n;       // 100
    const float tm1 = (float)(T - 1);

    const int n4 = (n + 3) / 4;
    const int blocks4 = (n4 + 255) / 256;     // pass-1 / fused grid

    if (ws_size >= (size_t)n && T <= 256) {
        unsigned char* st = (unsigned char*)d_ws;
        spike_time_kernel<<<blocks4, 256, 0, stream>>>(x, st, n, tm1);
        const int blocksBx = (n + 4095) / 4096;   // 256 for n=1M
        dim3 grid(blocksBx, T);
        write_onehot_c4_kernel<<<grid, 256, 0, stream>>>(st, out, n);
    } else {
        dim3 grid(blocks4, T);
        fused_onehot_kernel<<<grid, 256, 0, stream>>>(x, out, n, tm1);
    }
}

// Round 4
// 416.616 us; speedup vs baseline: 1.5894x; 1.0011x over previous
//
#include <hip/hip_runtime.h>
#include <math.h>

// TemporalEncoder: out[t, b, d] = (t == floor(sigmoid(x[b,d]) * (T-1))) ? 1 : 0
// B=256, D=4096, T=100. Output 419 MB fp32 -> pure write-BW bound.
//
// Structure (two passes, d_ws holds spike times as uchar):
//   Pass 1: spike times -> d_ws (1 MB, L2-resident afterwards; R2 counters
//           proved FETCH_SIZE ~0.5 MB across all 100 planes).
//   Pass 2: PERSISTENT sequential-stream writer (R5).
//
// Counter-verified lessons:
//   R2: nontemporal stores -> 2.2x WRITE_SIZE amplification (nt bypasses L2
//       write-back merging). Regular stores only.
//   R3: 16 consecutive elems/thread -> lane-stride-64B stores, 4x store
//       transactions per instruction. Stores must be lane-coalesced.
//   R4: coalesced but short-lived blocks (25K blocks, 1 dependent st-load
//       stall per 4 stores, then exit) -> 3.4 TB/s. Meanwhile rocclr fill
//       hits 6.25 TB/s at 10% occupancy: saturation comes from long
//       per-wave dependency-free store streams, not from occupancy.
//   R5: persistent grid: 1024 blocks x 100 chunks (4 KB) contiguous each;
//       st read for chunk j+1 pipelined ahead of chunk j's store, so the
//       steady-state store stream never waits on a load.

typedef __attribute__((ext_vector_type(4))) float f32x4;

__device__ __forceinline__ float sigmoidf_(float x) {
    return 1.0f / (1.0f + expf(-x));  // matches f32 expit to 0 ulp vs np ref (R1)
}

__device__ __forceinline__ f32x4 onehot4_(unsigned int sw, unsigned int tu) {
    f32x4 o;
    o.x = (((sw      ) & 0xffu) == tu) ? 1.0f : 0.0f;
    o.y = (((sw >>  8) & 0xffu) == tu) ? 1.0f : 0.0f;
    o.z = (((sw >> 16) & 0xffu) == tu) ? 1.0f : 0.0f;
    o.w = (((sw >> 24)        ) == tu) ? 1.0f : 0.0f;
    return o;
}

__global__ __launch_bounds__(256) void spike_time_kernel(
    const float* __restrict__ x, unsigned char* __restrict__ st,
    int n, float tm1) {
    const int e = (blockIdx.x * 256 + threadIdx.x) * 4;
    if (e + 3 < n) {
        f32x4 v = *reinterpret_cast<const f32x4*>(x + e);
        uchar4 s;
        s.x = (unsigned char)(int)(sigmoidf_(v.x) * tm1);
        s.y = (unsigned char)(int)(sigmoidf_(v.y) * tm1);
        s.z = (unsigned char)(int)(sigmoidf_(v.z) * tm1);
        s.w = (unsigned char)(int)(sigmoidf_(v.w) * tm1);
        *reinterpret_cast<uchar4*>(st + e) = s;
    } else {
        for (int i = e; i < n; ++i)
            st[i] = (unsigned char)(int)(sigmoidf_(x[i]) * tm1);
    }
}

// Pass 2: persistent streamer. Chunk = 1024 elems (4 KB). Each block owns
// `cpb` CONTIGUOUS chunks; per iteration each thread does one uint st-load
// (for the NEXT chunk, pipelined) and one f32x4 store (current chunk).
// Requires n % 1024 == 0 (true for n = 2^20).
__global__ __launch_bounds__(256) void write_onehot_persist_kernel(
    const unsigned char* __restrict__ st, float* __restrict__ out,
    int n, int total_chunks, int cpb) {
    const int cpp = n >> 10;                 // chunks per t-plane
    const int c0 = blockIdx.x * cpb;
    int cend = c0 + cpb;
    if (cend > total_chunks) cend = total_chunks;
    if (c0 >= cend) return;

    const int lane4 = threadIdx.x * 4;       // elem offset within chunk
    int t  = c0 / cpp;                       // once per block, uniform
    int lc = c0 - t * cpp;                   // chunk index within plane

    // software pipeline: st word for the current chunk, loaded one iter ahead
    unsigned int s_next =
        *reinterpret_cast<const unsigned int*>(st + (lc << 10) + lane4);
    float* op = out + (size_t)c0 * 1024 + lane4;

    for (int c = c0; c < cend; ++c) {
        const unsigned int s_cur = s_next;
        const unsigned int tu = (unsigned int)t;
        // advance plane-local position (uniform, no division)
        int lc_n = lc + 1, t_n = t;
        if (lc_n == cpp) { lc_n = 0; ++t_n; }
        if (c + 1 < cend)
            s_next = *reinterpret_cast<const unsigned int*>(
                st + (lc_n << 10) + lane4);
        *reinterpret_cast<f32x4*>(op) = onehot4_(s_cur, tu);
        op += 1024;
        lc = lc_n; t = t_n;
    }
}

// Fallback if d_ws is too small, T doesn't fit in a byte, or n % 1024 != 0.
__global__ __launch_bounds__(256) void fused_onehot_kernel(
    const float* __restrict__ x, float* __restrict__ out, int n, float tm1) {
    const int t = blockIdx.y;
    const int e = (blockIdx.x * 256 + threadIdx.x) * 4;
    if (e + 3 < n) {
        f32x4 v = *reinterpret_cast<const f32x4*>(x + e);
        f32x4 o;
        o.x = ((int)(sigmoidf_(v.x) * tm1) == t) ? 1.0f : 0.0f;
        o.y = ((int)(sigmoidf_(v.y) * tm1) == t) ? 1.0f : 0.0f;
        o.z = ((int)(sigmoidf_(v.z) * tm1) == t) ? 1.0f : 0.0f;
        o.w = ((int)(sigmoidf_(v.w) * tm1) == t) ? 1.0f : 0.0f;
        *reinterpret_cast<f32x4*>(out + (size_t)t * n + e) = o;
    } else {
        for (int i = e; i < n; ++i)
            out[(size_t)t * n + i] = ((int)(sigmoidf_(x[i]) * tm1) == t) ? 1.0f : 0.0f;
    }
}

extern "C" void kernel_launch(void* const* d_in, const int* in_sizes, int n_in,
                              void* d_out, int out_size, void* d_ws, size_t ws_size,
                              hipStream_t stream) {
    const float* x = (const float*)d_in[0];
    float* out = (float*)d_out;
    const int n = in_sizes[0];        // B*D = 1048576
    const int T = out_size / n;       // 100
    const float tm1 = (float)(T - 1);

    const int n4 = (n + 3) / 4;
    const int blocks4 = (n4 + 255) / 256;     // pass-1 / fused grid

    if (ws_size >= (size_t)n && T <= 256 && (n & 1023) == 0) {
        unsigned char* st = (unsigned char*)d_ws;
        spike_time_kernel<<<blocks4, 256, 0, stream>>>(x, st, n, tm1);
        const int total_chunks = (int)(((size_t)T * n) >> 10);  // 102400
        const int target_blocks = 1024;
        const int cpb = (total_chunks + target_blocks - 1) / target_blocks; // 100
        const int blocks = (total_chunks + cpb - 1) / cpb;                  // 1024
        write_onehot_persist_kernel<<<blocks, 256, 0, stream>>>(
            st, out, n, total_chunks, cpb);
    } else {
        dim3 grid(blocks4, T);
        fused_onehot_kernel<<<grid, 256, 0, stream>>>(x, out, n, tm1);
    }
}